// Round 6
// baseline (269.691 us; speedup 1.0000x reference)
//
#include <hip/hip_runtime.h>
#include <math.h>

#define B_ 32
#define C_ 3
#define H_ 256
#define W_ 832
#define HW_ (H_*W_)
#define K_ 100
#define RPB 16                  // rows per block
#define PARTS (H_/RPB)          // 16 parts per channel
#define NLOAD (W_/4)            // 208 threads carry pixels
#define BLK 256
#define CAP 2048
#define GRP 256                 // tie-group capacity in radix select
#define NCAND (C_*PARTS*K_)     // 4800 candidates per batch

typedef unsigned long long ull;

__device__ inline float fmax3(float a, float b, float c) {
    return fmaxf(fmaxf(a, b), c);
}

// Descending bitonic sort of N (power of two) 64-bit keys in LDS (small N).
template<int N>
__device__ inline void bitonic_sort_desc(ull* s) {
    for (int k = 2; k <= N; k <<= 1) {
        for (int j = k >> 1; j > 0; j >>= 1) {
            __syncthreads();
            for (int i = threadIdx.x; i < N; i += BLK) {
                int ixj = i ^ j;
                if (ixj > i) {
                    ull a = s[i], b = s[ixj];
                    bool up = ((i & k) == 0);
                    if (up ? (a < b) : (a > b)) { s[i] = b; s[ixj] = a; }
                }
            }
        }
    }
    __syncthreads();
}

// k-th largest 64-bit key among buf[0..cnt) via byte-wise radix select.
// Passes 7..6 scan buf; keys tied at the winning 16-bit score prefix are
// then compacted into a tiny group (expected a handful) and passes 5..0
// scan only the group (fallback to buf if group overflows GRP).
// Wave-aggregated histogram atomics + shfl suffix-scan.
__device__ ull radix_select(const ull* __restrict__ buf, int cnt, int k) {
    __shared__ unsigned hist[256];
    __shared__ unsigned wsum[4];
    __shared__ ull pref_s;
    __shared__ int k_s;
    __shared__ ull grp[GRP];
    __shared__ int gcnt;
    const int tid = threadIdx.x;
    const int lane = tid & 63;
    const int wv = tid >> 6;
    if (cnt < k) return 0ULL;               // uniform early-out
    if (tid == 0) { pref_s = 0ULL; k_s = k; gcnt = 0; }

    for (int pos = 7; pos >= 0; --pos) {
        __syncthreads();                    // pref_s/k_s visible; hist reusable
        // after the 2 high score-byte passes, compact the 16-bit tie group
        if (pos == 5) {
            const ull hi = pref_s;
            for (int i0 = 0; i0 < cnt; i0 += BLK) {
                const int i = i0 + tid;
                const ull key = (i < cnt) ? buf[i] : 0ULL;
                const bool sel = (i < cnt) && ((key >> 48) == hi);
                const ull m = __ballot(sel);
                const int nsel = (int)__popcll(m);
                int base = 0;
                if (lane == 0 && nsel) base = atomicAdd(&gcnt, nsel);
                base = __shfl(base, 0);
                const int rank = (int)__popcll(m & ((1ULL << lane) - 1ULL));
                if (sel && base + rank < GRP) grp[base + rank] = key;
            }
            __syncthreads();
        }
        const bool use_grp = (pos <= 5) && (gcnt <= GRP);
        const ull* src = use_grp ? grp : buf;
        const int scnt = use_grp ? gcnt : cnt;

        hist[tid] = 0;
        __syncthreads();
        const ull prefix = pref_s;
        const int kk = k_s;
        for (int i0 = 0; i0 < scnt; i0 += BLK) {
            const int i = i0 + tid;
            ull key = (i < scnt) ? src[i] : 0ULL;
            bool todo = (i < scnt) &&
                        ((pos == 7) || ((key >> (8 * (pos + 1))) == prefix));
            unsigned d = (unsigned)(key >> (8 * pos)) & 255u;
            // wave-aggregate same-digit lanes (<=4 leader rounds), then fallback
            #pragma unroll
            for (int it = 0; it < 4; ++it) {
                const ull act = __ballot(todo);
                if (act == 0ULL) break;
                const int leader = __ffsll((long long)act) - 1;
                const unsigned dl = (unsigned)__shfl((int)d, leader);
                const bool same = todo && (d == dl);
                const ull ms = __ballot(same);
                if (lane == leader) atomicAdd(&hist[dl], (unsigned)__popcll(ms));
                if (same) todo = false;
            }
            if (todo) atomicAdd(&hist[d], 1u);
        }
        __syncthreads();
        // suffix scan: S[t] = sum_{i>=t} hist[i]
        const unsigned h = hist[tid];
        unsigned v = h;
        #pragma unroll
        for (int off = 1; off < 64; off <<= 1) {
            const unsigned o = __shfl_down(v, off);
            if (lane + off < 64) v += o;
        }
        if (lane == 0) wsum[wv] = v;
        __syncthreads();
        unsigned carry = 0;
        #pragma unroll
        for (int w = 0; w < 4; ++w) if (w > wv) carry += wsum[w];
        const unsigned S = v + carry;       // matching keys with digit >= tid
        const unsigned above = S - h;       // digit > tid
        if (S >= (unsigned)kk && above < (unsigned)kk) {   // unique winner
            pref_s = (prefix << 8) | (ull)tid;
            k_s = kk - (int)above;
        }
    }
    __syncthreads();
    return pref_s;
}

// ---------------------------------------------------------------------------
// Kernel 1: separable 3x3 peak detect + exact top-100 per (channel, 16-row
// part). Barrier-free row loop, register-rotated rows, wave-shuffle
// horizontal neighbors, ONE wave atomic per row (4 merged ballots).
// key = (value_bits<<32) | ~((c<<18)|pixel): unified comparator
// (score desc, channel asc, pixel asc) == composed jax two-stage top_k.
// ---------------------------------------------------------------------------
__global__ void __launch_bounds__(BLK) topk_part_kernel(
        const float* __restrict__ heat, ull* __restrict__ part_out) {
    const int chan = blockIdx.x / PARTS;   // b*C + c
    const int c    = chan % C_;
    const int part = blockIdx.x % PARTS;
    const float* __restrict__ hp = heat + (size_t)chan * HW_;
    const int r0 = part * RPB;
    const int tid = threadIdx.x;
    const bool active = tid < NLOAD;
    const int x4 = tid * 4;
    const int lane = tid & 63;
    const ull below = (1ULL << lane) - 1ULL;

    __shared__ ull buf[CAP];
    __shared__ int cnt;
    if (tid == 0) cnt = 0;
    __syncthreads();   // cnt=0 visible

    const bool needL = active && (lane == 0) && (tid != 0);     // 64,128,192
    const bool needR = active && (lane == 63);                   // 63,127,191
    const int colL = x4 - 1;
    const int colR = x4 + 4;

    float4 rA, rB, rC, rD;
    float lA=0.f,lB=0.f,lC=0.f,lD=0.f, qA=0.f,qB=0.f,qC=0.f,qD=0.f;
    {
        const int ym1 = (r0 == 0) ? 0 : r0 - 1;
        const int yp1 = (r0 == H_ - 1) ? r0 : r0 + 1;
        if (active) {
            rA = reinterpret_cast<const float4*>(hp + (size_t)ym1 * W_)[tid];
            rB = reinterpret_cast<const float4*>(hp + (size_t)r0  * W_)[tid];
            rC = reinterpret_cast<const float4*>(hp + (size_t)yp1 * W_)[tid];
        }
        if (needL) { lA = hp[ym1*W_+colL]; lB = hp[r0*W_+colL]; lC = hp[yp1*W_+colL]; }
        if (needR) { qA = hp[ym1*W_+colR]; qB = hp[r0*W_+colR]; qC = hp[yp1*W_+colR]; }
    }

    for (int r = 0; r < RPB; ++r) {
        const int y = r0 + r;
        const int yn = (y + 2 > H_ - 1) ? H_ - 1 : y + 2;
        if (active) rD = reinterpret_cast<const float4*>(hp + (size_t)yn * W_)[tid];
        if (needL) lD = hp[yn*W_+colL];
        if (needR) qD = hp[yn*W_+colR];

        float4 vm;
        bool pk0 = false, pk1 = false, pk2 = false, pk3 = false;
        if (active) {
            vm.x = fmax3(rA.x, rB.x, rC.x);
            vm.y = fmax3(rA.y, rB.y, rC.y);
            vm.z = fmax3(rA.z, rB.z, rC.z);
            vm.w = fmax3(rA.w, rB.w, rC.w);
        }
        float left  = __shfl_up(vm.w, 1);
        float right = __shfl_down(vm.x, 1);
        if (active) {
            if (lane == 0)  left  = (tid == 0) ? -INFINITY : fmax3(lA, lB, lC);
            if (lane == 63) right = fmax3(qA, qB, qC);
            if (tid == NLOAD - 1) right = -INFINITY;
            pk0 = (rB.x >= left) && (rB.x >= vm.x) && (rB.x >= vm.y);
            pk1 = (rB.y >= vm.x) && (rB.y >= vm.y) && (rB.y >= vm.z);
            pk2 = (rB.z >= vm.y) && (rB.z >= vm.z) && (rB.z >= vm.w);
            pk3 = (rB.w >= vm.z) && (rB.w >= vm.w) && (rB.w >= right);
        }
        // merged append: 4 ballots, one wave atomic, prefix-popcount offsets
        const ull m0 = __ballot(pk0);
        const ull m1 = __ballot(pk1);
        const ull m2 = __ballot(pk2);
        const ull m3 = __ballot(pk3);
        const int n0 = (int)__popcll(m0);
        const int n1 = (int)__popcll(m1);
        const int n2 = (int)__popcll(m2);
        const int n3 = (int)__popcll(m3);
        const int tot = n0 + n1 + n2 + n3;
        int base = 0;
        if (lane == 0 && tot) base = atomicAdd(&cnt, tot);
        base = __shfl(base, 0);
        if (tot) {
            const unsigned pbase = (unsigned)(((unsigned)c << 18) | (y * W_ + x4));
            if (pk0) {
                const int pos = base + (int)__popcll(m0 & below);
                if (pos < CAP) buf[pos] =
                    ((ull)__float_as_uint(rB.x) << 32) | (ull)(~pbase);
            }
            if (pk1) {
                const int pos = base + n0 + (int)__popcll(m1 & below);
                if (pos < CAP) buf[pos] =
                    ((ull)__float_as_uint(rB.y) << 32) | (ull)(~(pbase + 1));
            }
            if (pk2) {
                const int pos = base + n0 + n1 + (int)__popcll(m2 & below);
                if (pos < CAP) buf[pos] =
                    ((ull)__float_as_uint(rB.z) << 32) | (ull)(~(pbase + 2));
            }
            if (pk3) {
                const int pos = base + n0 + n1 + n2 + (int)__popcll(m3 & below);
                if (pos < CAP) buf[pos] =
                    ((ull)__float_as_uint(rB.w) << 32) | (ull)(~(pbase + 3));
            }
        }
        rA = rB; rB = rC; rC = rD;
        lA = lB; lB = lC; lC = lD;
        qA = qB; qB = qC; qC = qD;
    }
    __syncthreads();   // cnt + buf final

    const int cc = (cnt < CAP) ? cnt : CAP;
    const ull thr = radix_select(buf, cc, K_);

    __shared__ int ocnt;
    if (tid == 0) ocnt = 0;
    __syncthreads();
    ull* o = part_out + (size_t)blockIdx.x * K_;
    for (int i0 = 0; i0 < cc; i0 += BLK) {
        const int i = i0 + tid;
        const ull key = (i < cc) ? buf[i] : 0ULL;
        const bool sel = (i < cc) && (key >= thr) && (key != 0ULL);
        const ull m = __ballot(sel);
        const int nsel = (int)__popcll(m);
        int base = 0;
        if (lane == 0 && nsel) base = atomicAdd(&ocnt, nsel);
        base = __shfl(base, 0);
        const int rank = (int)__popcll(m & below);
        if (sel && base + rank < K_) o[base + rank] = key;
    }
    __syncthreads();
    const int oc = (ocnt < K_) ? ocnt : K_;
    for (int i = oc + tid; i < K_; i += BLK) o[i] = 0ULL;
}

// ---------------------------------------------------------------------------
// Kernel 2 (fused merge + geometry): per-batch top-100 of 48x100 candidates
// (radix-select + compact + sort-128), then threads 0..99 compute the output
// rows directly.
// ---------------------------------------------------------------------------
__global__ void __launch_bounds__(BLK) merge_geom_kernel(
        const ull* __restrict__ part_keys, const float* __restrict__ reg,
        const float* __restrict__ trans, const float* __restrict__ Km,
        const float* __restrict__ sz, const float* __restrict__ hcam,
        const float* __restrict__ dimen, float* __restrict__ out) {
    const int b = blockIdx.x;
    const int tid = threadIdx.x;
    const int lane = tid & 63;
    __shared__ ull buf[NCAND];
    __shared__ ull sel_s[128];
    __shared__ int ocnt;
    const ull* src = part_keys + (size_t)b * NCAND;
    for (int i = tid; i < NCAND; i += BLK) buf[i] = src[i];
    if (tid < 128) sel_s[tid] = 0ULL;
    if (tid == 0) ocnt = 0;
    __syncthreads();

    const ull thr = radix_select(buf, NCAND, K_);
    for (int i0 = 0; i0 < NCAND; i0 += BLK) {
        const int i = i0 + tid;
        const ull key = (i < NCAND) ? buf[i] : 0ULL;
        const bool sel = (i < NCAND) && (key >= thr) && (key != 0ULL);
        const ull m = __ballot(sel);
        const int nsel = (int)__popcll(m);
        int base = 0;
        if (lane == 0 && nsel) base = atomicAdd(&ocnt, nsel);
        base = __shfl(base, 0);
        const int rank = (int)__popcll(m & ((1ULL << lane) - 1ULL));
        if (sel && base + rank < 128) sel_s[base + rank] = key;
    }
    bitonic_sort_desc<128>(sel_s);   // has leading __syncthreads

    // ---- geometry for ranks 0..99 ----
    if (tid >= K_) return;
    const int n = b * K_ + tid;
    const ull key = sel_s[tid];
    const unsigned tie = ~(unsigned)(key & 0xFFFFFFFFULL);
    const float score = __uint_as_float((unsigned)(key >> 32));
    const float clsf  = (float)((tie >> 18) & 3u);
    unsigned hw = tie & 0x3FFFFu;
    if (hw >= HW_) hw = 0;          // pad entries: score==0, row zeroed
    const float xs = (float)(hw % W_);
    const float ys = (float)(hw / W_);

    const float* rg = reg + (size_t)b * 4 * HW_;
    const float delta = rg[hw];
    const float off_u = rg[HW_ + hw];
    const float ori0  = rg[2 * HW_ + hw];
    const float ori1  = rg[3 * HW_ + hw];

    const float* T = trans + b * 9;
    const float t00=T[0], t01=T[1], t02=T[2], t10=T[3], t11=T[4], t12=T[5],
                t20=T[6], t21=T[7], t22=T[8];
    const float det3 = t00*(t11*t22 - t12*t21) - t01*(t10*t22 - t12*t20)
                     + t02*(t10*t21 - t11*t20);
    const float idt = 1.0f / det3;
    const float i00 = (t11*t22 - t12*t21)*idt;
    const float i01 = (t02*t21 - t01*t22)*idt;
    const float i02 = (t01*t12 - t02*t11)*idt;

    const float pu = xs + off_u;
    const float img_x = i00*pu + i01*ys + i02;

    const float* Kb = Km + b * 9;
    const float k00=Kb[0],k01=Kb[1],k02=Kb[2],k10=Kb[3],k11=Kb[4],k12=Kb[5],
                k20=Kb[6],k21=Kb[7],k22=Kb[8];
    const float fx = k00, fy = k11, cx = k02;
    const float h = hcam[b];
    float d0 = dimen[b*3+0], d1 = dimen[b*3+1], d2 = dimen[b*3+2];
    if (!isfinite(d0)) d0 = 3.88f;
    if (!isfinite(d1)) d1 = 1.63f;
    if (!isfinite(d2)) d2 = 1.53f;

    const float h_ref = h - d1 * 0.5f;
    const float fyh = fy * fabsf(h_ref);
    const float log_dv_ref = logf(fmaxf(fyh, 1e-7f) / 28.01f);
    const float log_dv = fminf(fmaxf(log_dv_ref + delta, -4.0f), 8.0f);
    const float depth = fminf(fmaxf(fyh * expf(-log_dv), 0.5f), 120.0f);
    const float px = (img_x - cx) * depth / fx;

    const float PI_F = 3.14159265358979323846f;
    const float ray = atanf(px / (depth + 1e-7f));
    float alpha = atanf(ori0 / (ori1 + 1e-7f));
    alpha += (ori1 >= 0.0f) ? -1.5707963267948966f : 1.5707963267948966f;
    float roty = alpha + ray;
    if (roty >  PI_F) roty -= 6.283185307179586f;
    if (roty < -PI_F) roty += 6.283185307179586f;

    const float cosr = cosf(roty), sinr = sinf(roty);
    const float cx8[8] = {-0.5f, 0.5f, 0.5f, 0.5f, 0.5f,-0.5f,-0.5f,-0.5f};
    const float cy8[8] = {-1.0f,-1.0f, 0.0f, 0.0f,-1.0f,-1.0f, 0.0f, 0.0f};
    const float cz8[8] = {-0.5f,-0.5f,-0.5f, 0.5f, 0.5f, 0.5f, 0.5f,-0.5f};
    float umin = 1e30f, umax = -1e30f, vmin = 1e30f, vmax = -1e30f;
    #pragma unroll
    for (int i = 0; i < 8; ++i) {
        const float xc = d0 * cx8[i];
        const float yc = d1 * cy8[i];
        const float zc = d2 * cz8[i];
        const float X = cosr*xc + sinr*zc + px;
        const float Y = yc + h;
        const float Z = -sinr*xc + cosr*zc + depth;
        const float w = k20*X + k21*Y + k22*Z;
        const float u = (k00*X + k01*Y + k02*Z) / w;
        const float v = (k10*X + k11*Y + k12*Z) / w;
        umin = fminf(umin, u); umax = fmaxf(umax, u);
        vmin = fminf(vmin, v); vmax = fmaxf(vmax, v);
    }
    const float img_w = sz[0], img_h = sz[1];
    const float xmin = fminf(fmaxf(umin, 0.0f), img_w);
    const float xmax = fminf(fmaxf(umax, 0.0f), img_w);
    const float ymin = fminf(fmaxf(vmin, 0.0f), img_h);
    const float ymax = fminf(fmaxf(vmax, 0.0f), img_h);

    const float keep = (score > 0.25f) ? 1.0f : 0.0f;
    float* o = out + (size_t)n * 14;
    o[0]  = clsf  * keep;
    o[1]  = alpha * keep;
    o[2]  = xmin  * keep;
    o[3]  = ymin  * keep;
    o[4]  = xmax  * keep;
    o[5]  = ymax  * keep;
    o[6]  = d1    * keep;   // pred_dims = roll(dims,-1)
    o[7]  = d2    * keep;
    o[8]  = d0    * keep;
    o[9]  = px    * keep;
    o[10] = h     * keep;
    o[11] = depth * keep;
    o[12] = roty  * keep;
    o[13] = score * keep;
}

extern "C" void kernel_launch(void* const* d_in, const int* in_sizes, int n_in,
                              void* d_out, int out_size, void* d_ws, size_t ws_size,
                              hipStream_t stream) {
    const float* heat  = (const float*)d_in[0];  // (32,3,256,832)
    const float* reg   = (const float*)d_in[1];  // (32,4,256,832)
    const float* trans = (const float*)d_in[2];  // (32,3,3)
    const float* Kmat  = (const float*)d_in[3];  // (32,3,3)
    const float* sz    = (const float*)d_in[4];  // (32,2)
    const float* hcam  = (const float*)d_in[5];  // (32,)
    const float* dimen = (const float*)d_in[6];  // (32,3)
    float* out = (float*)d_out;

    ull* part_keys = (ull*)d_ws;   // 1536*100*8 = 1,228,800 B

    topk_part_kernel<<<B_ * C_ * PARTS, BLK, 0, stream>>>(heat, part_keys);
    merge_geom_kernel<<<B_, BLK, 0, stream>>>(
        part_keys, reg, trans, Kmat, sz, hcam, dimen, out);
}

// Round 7
// 265.399 us; speedup vs baseline: 1.0162x; 1.0162x over previous
//
#include <hip/hip_runtime.h>
#include <math.h>

#define B_ 32
#define C_ 3
#define H_ 256
#define W_ 832
#define HW_ (H_*W_)
#define K_ 100
#define RPB 16                  // rows per block
#define PARTS (H_/RPB)          // 16 parts per channel
#define NLOAD (W_/4)            // 208 threads carry pixels
#define BLK 256
#define CAP 2048
#define GRP 256                 // tie-group capacity in radix select
#define NCAND (C_*PARTS*K_)     // 4800 candidates per batch

typedef unsigned long long ull;

__device__ inline float fmax3(float a, float b, float c) {
    return fmaxf(fmaxf(a, b), c);
}

// k-th largest 64-bit key among buf[0..cnt) via byte-wise radix select.
// Passes 7..6 scan buf; keys tied at the winning 16-bit score prefix are
// then compacted into a tiny group and passes 5..0 scan only the group
// (fallback to buf if the group overflows GRP). Wave-aggregated histogram
// atomics + shfl suffix-scan. All threads return the same threshold.
__device__ ull radix_select(const ull* __restrict__ buf, int cnt, int k) {
    __shared__ unsigned hist[256];
    __shared__ unsigned wsum[4];
    __shared__ ull pref_s;
    __shared__ int k_s;
    __shared__ ull grp[GRP];
    __shared__ int gcnt;
    const int tid = threadIdx.x;
    const int lane = tid & 63;
    const int wv = tid >> 6;
    if (cnt < k) return 0ULL;               // uniform early-out
    if (tid == 0) { pref_s = 0ULL; k_s = k; gcnt = 0; }

    for (int pos = 7; pos >= 0; --pos) {
        __syncthreads();                    // pref_s/k_s visible; hist reusable
        // after the 2 high score-byte passes, compact the 16-bit tie group
        if (pos == 5) {
            const ull hi = pref_s;
            for (int i0 = 0; i0 < cnt; i0 += BLK) {
                const int i = i0 + tid;
                const ull key = (i < cnt) ? buf[i] : 0ULL;
                const bool sel = (i < cnt) && ((key >> 48) == hi);
                const ull m = __ballot(sel);
                const int nsel = (int)__popcll(m);
                int base = 0;
                if (lane == 0 && nsel) base = atomicAdd(&gcnt, nsel);
                base = __shfl(base, 0);
                const int rank = (int)__popcll(m & ((1ULL << lane) - 1ULL));
                if (sel && base + rank < GRP) grp[base + rank] = key;
            }
            __syncthreads();
        }
        const bool use_grp = (pos <= 5) && (gcnt <= GRP);
        const ull* src = use_grp ? grp : buf;
        const int scnt = use_grp ? gcnt : cnt;

        hist[tid] = 0;
        __syncthreads();
        const ull prefix = pref_s;
        const int kk = k_s;
        for (int i0 = 0; i0 < scnt; i0 += BLK) {
            const int i = i0 + tid;
            ull key = (i < scnt) ? src[i] : 0ULL;
            bool todo = (i < scnt) &&
                        ((pos == 7) || ((key >> (8 * (pos + 1))) == prefix));
            unsigned d = (unsigned)(key >> (8 * pos)) & 255u;
            // wave-aggregate same-digit lanes (<=4 leader rounds), then fallback
            #pragma unroll
            for (int it = 0; it < 4; ++it) {
                const ull act = __ballot(todo);
                if (act == 0ULL) break;
                const int leader = __ffsll((long long)act) - 1;
                const unsigned dl = (unsigned)__shfl((int)d, leader);
                const bool same = todo && (d == dl);
                const ull ms = __ballot(same);
                if (lane == leader) atomicAdd(&hist[dl], (unsigned)__popcll(ms));
                if (same) todo = false;
            }
            if (todo) atomicAdd(&hist[d], 1u);
        }
        __syncthreads();
        // suffix scan: S[t] = sum_{i>=t} hist[i]
        const unsigned h = hist[tid];
        unsigned v = h;
        #pragma unroll
        for (int off = 1; off < 64; off <<= 1) {
            const unsigned o = __shfl_down(v, off);
            if (lane + off < 64) v += o;
        }
        if (lane == 0) wsum[wv] = v;
        __syncthreads();
        unsigned carry = 0;
        #pragma unroll
        for (int w = 0; w < 4; ++w) if (w > wv) carry += wsum[w];
        const unsigned S = v + carry;       // matching keys with digit >= tid
        const unsigned above = S - h;       // digit > tid
        if (S >= (unsigned)kk && above < (unsigned)kk) {   // unique winner
            pref_s = (prefix << 8) | (ull)tid;
            k_s = kk - (int)above;
        }
    }
    __syncthreads();
    return pref_s;
}

// ---------------------------------------------------------------------------
// Kernel 1: separable 3x3 peak detect + exact top-100 per (channel, 16-row
// part). Barrier-free row loop, 6-row register pipeline (load->use distance
// 3 iterations to cover HBM latency), wave-shuffle horizontal neighbors,
// ONE wave atomic per row (4 merged ballots). Fully unrolled so rotations
// are register renames.
// key = (value_bits<<32) | ~((c<<18)|pixel): unified comparator
// (score desc, channel asc, pixel asc) == composed jax two-stage top_k.
// ---------------------------------------------------------------------------
__global__ void __launch_bounds__(BLK) topk_part_kernel(
        const float* __restrict__ heat, ull* __restrict__ part_out) {
    const int chan = blockIdx.x / PARTS;   // b*C + c
    const int c    = chan % C_;
    const int part = blockIdx.x % PARTS;
    const float* __restrict__ hp = heat + (size_t)chan * HW_;
    const int r0 = part * RPB;
    const int tid = threadIdx.x;
    const bool active = tid < NLOAD;
    const int x4 = tid * 4;
    const int lane = tid & 63;
    const ull below = (1ULL << lane) - 1ULL;

    __shared__ ull buf[CAP];
    __shared__ int cnt;
    if (tid == 0) cnt = 0;
    __syncthreads();   // cnt=0 visible

    const bool needL = active && (lane == 0) && (tid != 0);     // 64,128,192
    const bool needR = active && (lane == 63);                   // 63,127,191
    const int colL = x4 - 1;
    const int colR = x4 + 4;

    float4 rA, rB, rC, rD, rE, rF;
    float lA=0.f,lB=0.f,lC=0.f,lD=0.f,lE=0.f,lF=0.f;
    float qA=0.f,qB=0.f,qC=0.f,qD=0.f,qE=0.f,qF=0.f;
    {
        const int ym1 = (r0 == 0) ? 0 : r0 - 1;
        const int yp1 = (r0 + 1 > H_ - 1) ? H_ - 1 : r0 + 1;
        const int yp2 = (r0 + 2 > H_ - 1) ? H_ - 1 : r0 + 2;
        const int yp3 = (r0 + 3 > H_ - 1) ? H_ - 1 : r0 + 3;
        if (active) {
            rA = reinterpret_cast<const float4*>(hp + (size_t)ym1 * W_)[tid];
            rB = reinterpret_cast<const float4*>(hp + (size_t)r0  * W_)[tid];
            rC = reinterpret_cast<const float4*>(hp + (size_t)yp1 * W_)[tid];
            rD = reinterpret_cast<const float4*>(hp + (size_t)yp2 * W_)[tid];
            rE = reinterpret_cast<const float4*>(hp + (size_t)yp3 * W_)[tid];
        }
        if (needL) {
            lA = hp[ym1*W_+colL]; lB = hp[r0*W_+colL]; lC = hp[yp1*W_+colL];
            lD = hp[yp2*W_+colL]; lE = hp[yp3*W_+colL];
        }
        if (needR) {
            qA = hp[ym1*W_+colR]; qB = hp[r0*W_+colR]; qC = hp[yp1*W_+colR];
            qD = hp[yp2*W_+colR]; qE = hp[yp3*W_+colR];
        }
    }

    #pragma unroll
    for (int r = 0; r < RPB; ++r) {
        const int y = r0 + r;
        const int yn = (y + 4 > H_ - 1) ? H_ - 1 : y + 4;
        if (active) rF = reinterpret_cast<const float4*>(hp + (size_t)yn * W_)[tid];
        if (needL) lF = hp[yn*W_+colL];
        if (needR) qF = hp[yn*W_+colR];

        float4 vm;
        bool pk0 = false, pk1 = false, pk2 = false, pk3 = false;
        if (active) {
            vm.x = fmax3(rA.x, rB.x, rC.x);
            vm.y = fmax3(rA.y, rB.y, rC.y);
            vm.z = fmax3(rA.z, rB.z, rC.z);
            vm.w = fmax3(rA.w, rB.w, rC.w);
        }
        float left  = __shfl_up(vm.w, 1);
        float right = __shfl_down(vm.x, 1);
        if (active) {
            if (lane == 0)  left  = (tid == 0) ? -INFINITY : fmax3(lA, lB, lC);
            if (lane == 63) right = fmax3(qA, qB, qC);
            if (tid == NLOAD - 1) right = -INFINITY;
            pk0 = (rB.x >= left) && (rB.x >= vm.x) && (rB.x >= vm.y);
            pk1 = (rB.y >= vm.x) && (rB.y >= vm.y) && (rB.y >= vm.z);
            pk2 = (rB.z >= vm.y) && (rB.z >= vm.z) && (rB.z >= vm.w);
            pk3 = (rB.w >= vm.z) && (rB.w >= vm.w) && (rB.w >= right);
        }
        // merged append: 4 ballots, one wave atomic, prefix-popcount offsets
        const ull m0 = __ballot(pk0);
        const ull m1 = __ballot(pk1);
        const ull m2 = __ballot(pk2);
        const ull m3 = __ballot(pk3);
        const int n0 = (int)__popcll(m0);
        const int n1 = (int)__popcll(m1);
        const int n2 = (int)__popcll(m2);
        const int n3 = (int)__popcll(m3);
        const int tot = n0 + n1 + n2 + n3;
        int base = 0;
        if (lane == 0 && tot) base = atomicAdd(&cnt, tot);
        base = __shfl(base, 0);
        if (tot) {
            const unsigned pbase = (unsigned)(((unsigned)c << 18) | (y * W_ + x4));
            if (pk0) {
                const int pos = base + (int)__popcll(m0 & below);
                if (pos < CAP) buf[pos] =
                    ((ull)__float_as_uint(rB.x) << 32) | (ull)(~pbase);
            }
            if (pk1) {
                const int pos = base + n0 + (int)__popcll(m1 & below);
                if (pos < CAP) buf[pos] =
                    ((ull)__float_as_uint(rB.y) << 32) | (ull)(~(pbase + 1));
            }
            if (pk2) {
                const int pos = base + n0 + n1 + (int)__popcll(m2 & below);
                if (pos < CAP) buf[pos] =
                    ((ull)__float_as_uint(rB.z) << 32) | (ull)(~(pbase + 2));
            }
            if (pk3) {
                const int pos = base + n0 + n1 + n2 + (int)__popcll(m3 & below);
                if (pos < CAP) buf[pos] =
                    ((ull)__float_as_uint(rB.w) << 32) | (ull)(~(pbase + 3));
            }
        }
        rA = rB; rB = rC; rC = rD; rD = rE; rE = rF;
        lA = lB; lB = lC; lC = lD; lD = lE; lE = lF;
        qA = qB; qB = qC; qC = qD; qD = qE; qE = qF;
    }
    __syncthreads();   // cnt + buf final

    const int cc = (cnt < CAP) ? cnt : CAP;
    const ull thr = radix_select(buf, cc, K_);

    __shared__ int ocnt;
    if (tid == 0) ocnt = 0;
    __syncthreads();
    ull* o = part_out + (size_t)blockIdx.x * K_;
    for (int i0 = 0; i0 < cc; i0 += BLK) {
        const int i = i0 + tid;
        const ull key = (i < cc) ? buf[i] : 0ULL;
        const bool sel = (i < cc) && (key >= thr) && (key != 0ULL);
        const ull m = __ballot(sel);
        const int nsel = (int)__popcll(m);
        int base = 0;
        if (lane == 0 && nsel) base = atomicAdd(&ocnt, nsel);
        base = __shfl(base, 0);
        const int rank = (int)__popcll(m & below);
        if (sel && base + rank < K_) o[base + rank] = key;
    }
    __syncthreads();
    const int oc = (ocnt < K_) ? ocnt : K_;
    for (int i = oc + tid; i < K_; i += BLK) o[i] = 0ULL;
}

// ---------------------------------------------------------------------------
// Kernel 2 (fused merge + geometry): per-batch top-100 of 48x100 candidates
// (radix-select + compact), then barrier-free rank-by-comparison (keys are
// unique -> exactly 100 selected; rank = #{keys > mine}) and geometry
// scattered to the output row = rank.
// ---------------------------------------------------------------------------
__global__ void __launch_bounds__(BLK) merge_geom_kernel(
        const ull* __restrict__ part_keys, const float* __restrict__ reg,
        const float* __restrict__ trans, const float* __restrict__ Km,
        const float* __restrict__ sz, const float* __restrict__ hcam,
        const float* __restrict__ dimen, float* __restrict__ out) {
    const int b = blockIdx.x;
    const int tid = threadIdx.x;
    const int lane = tid & 63;
    __shared__ ull buf[NCAND];
    __shared__ ull sel_s[128];
    __shared__ int ocnt;
    const ull* srcg = part_keys + (size_t)b * NCAND;
    for (int i = tid; i < NCAND; i += BLK) buf[i] = srcg[i];
    if (tid == 0) ocnt = 0;
    __syncthreads();

    const ull thr = radix_select(buf, NCAND, K_);
    for (int i0 = 0; i0 < NCAND; i0 += BLK) {
        const int i = i0 + tid;
        const ull key = (i < NCAND) ? buf[i] : 0ULL;
        const bool sel = (i < NCAND) && (key >= thr) && (key != 0ULL);
        const ull m = __ballot(sel);
        const int nsel = (int)__popcll(m);
        int base = 0;
        if (lane == 0 && nsel) base = atomicAdd(&ocnt, nsel);
        base = __shfl(base, 0);
        const int rk = (int)__popcll(m & ((1ULL << lane) - 1ULL));
        if (sel && base + rk < 128) sel_s[base + rk] = key;
    }
    __syncthreads();
    const int oc = (ocnt < 128) ? ocnt : 128;

    // rank by pairwise comparison (LDS broadcast reads, no barriers)
    int rank = -1;
    ull key = 0ULL;
    if (tid < oc) {
        key = sel_s[tid];
        int r = 0;
        for (int j = 0; j < oc; ++j) r += (sel_s[j] > key) ? 1 : 0;
        rank = r;
    } else if (tid < K_ && tid >= oc) {
        // pathological underfill: emit zero rows for missing ranks
        float* o = out + ((size_t)b * K_ + tid) * 14;
        #pragma unroll
        for (int j = 0; j < 14; ++j) o[j] = 0.0f;
    }
    if (rank < 0 || rank >= K_) return;

    // ---- geometry; output row = rank ----
    const unsigned tie = ~(unsigned)(key & 0xFFFFFFFFULL);
    const float score = __uint_as_float((unsigned)(key >> 32));
    const float clsf  = (float)((tie >> 18) & 3u);
    unsigned hw = tie & 0x3FFFFu;
    if (hw >= HW_) hw = 0;
    const float xs = (float)(hw % W_);
    const float ys = (float)(hw / W_);

    const float* rg = reg + (size_t)b * 4 * HW_;
    const float delta = rg[hw];
    const float off_u = rg[HW_ + hw];
    const float ori0  = rg[2 * HW_ + hw];
    const float ori1  = rg[3 * HW_ + hw];

    const float* T = trans + b * 9;
    const float t00=T[0], t01=T[1], t02=T[2], t10=T[3], t11=T[4], t12=T[5],
                t20=T[6], t21=T[7], t22=T[8];
    const float det3 = t00*(t11*t22 - t12*t21) - t01*(t10*t22 - t12*t20)
                     + t02*(t10*t21 - t11*t20);
    const float idt = 1.0f / det3;
    const float i00 = (t11*t22 - t12*t21)*idt;
    const float i01 = (t02*t21 - t01*t22)*idt;
    const float i02 = (t01*t12 - t02*t11)*idt;

    const float pu = xs + off_u;
    const float img_x = i00*pu + i01*ys + i02;

    const float* Kb = Km + b * 9;
    const float k00=Kb[0],k01=Kb[1],k02=Kb[2],k10=Kb[3],k11=Kb[4],k12=Kb[5],
                k20=Kb[6],k21=Kb[7],k22=Kb[8];
    const float fx = k00, fy = k11, cx = k02;
    const float h = hcam[b];
    float d0 = dimen[b*3+0], d1 = dimen[b*3+1], d2 = dimen[b*3+2];
    if (!isfinite(d0)) d0 = 3.88f;
    if (!isfinite(d1)) d1 = 1.63f;
    if (!isfinite(d2)) d2 = 1.53f;

    const float h_ref = h - d1 * 0.5f;
    const float fyh = fy * fabsf(h_ref);
    const float log_dv_ref = logf(fmaxf(fyh, 1e-7f) / 28.01f);
    const float log_dv = fminf(fmaxf(log_dv_ref + delta, -4.0f), 8.0f);
    const float depth = fminf(fmaxf(fyh * expf(-log_dv), 0.5f), 120.0f);
    const float px = (img_x - cx) * depth / fx;

    const float PI_F = 3.14159265358979323846f;
    const float ray = atanf(px / (depth + 1e-7f));
    float alpha = atanf(ori0 / (ori1 + 1e-7f));
    alpha += (ori1 >= 0.0f) ? -1.5707963267948966f : 1.5707963267948966f;
    float roty = alpha + ray;
    if (roty >  PI_F) roty -= 6.283185307179586f;
    if (roty < -PI_F) roty += 6.283185307179586f;

    const float cosr = cosf(roty), sinr = sinf(roty);
    const float cx8[8] = {-0.5f, 0.5f, 0.5f, 0.5f, 0.5f,-0.5f,-0.5f,-0.5f};
    const float cy8[8] = {-1.0f,-1.0f, 0.0f, 0.0f,-1.0f,-1.0f, 0.0f, 0.0f};
    const float cz8[8] = {-0.5f,-0.5f,-0.5f, 0.5f, 0.5f, 0.5f, 0.5f,-0.5f};
    float umin = 1e30f, umax = -1e30f, vmin = 1e30f, vmax = -1e30f;
    #pragma unroll
    for (int i = 0; i < 8; ++i) {
        const float xc = d0 * cx8[i];
        const float yc = d1 * cy8[i];
        const float zc = d2 * cz8[i];
        const float X = cosr*xc + sinr*zc + px;
        const float Y = yc + h;
        const float Z = -sinr*xc + cosr*zc + depth;
        const float w = k20*X + k21*Y + k22*Z;
        const float u = (k00*X + k01*Y + k02*Z) / w;
        const float v = (k10*X + k11*Y + k12*Z) / w;
        umin = fminf(umin, u); umax = fmaxf(umax, u);
        vmin = fminf(vmin, v); vmax = fmaxf(vmax, v);
    }
    const float img_w = sz[0], img_h = sz[1];
    const float xmin = fminf(fmaxf(umin, 0.0f), img_w);
    const float xmax = fminf(fmaxf(umax, 0.0f), img_w);
    const float ymin = fminf(fmaxf(vmin, 0.0f), img_h);
    const float ymax = fminf(fmaxf(vmax, 0.0f), img_h);

    const float keep = (score > 0.25f) ? 1.0f : 0.0f;
    float* o = out + ((size_t)b * K_ + rank) * 14;
    o[0]  = clsf  * keep;
    o[1]  = alpha * keep;
    o[2]  = xmin  * keep;
    o[3]  = ymin  * keep;
    o[4]  = xmax  * keep;
    o[5]  = ymax  * keep;
    o[6]  = d1    * keep;   // pred_dims = roll(dims,-1)
    o[7]  = d2    * keep;
    o[8]  = d0    * keep;
    o[9]  = px    * keep;
    o[10] = h     * keep;
    o[11] = depth * keep;
    o[12] = roty  * keep;
    o[13] = score * keep;
}

extern "C" void kernel_launch(void* const* d_in, const int* in_sizes, int n_in,
                              void* d_out, int out_size, void* d_ws, size_t ws_size,
                              hipStream_t stream) {
    const float* heat  = (const float*)d_in[0];  // (32,3,256,832)
    const float* reg   = (const float*)d_in[1];  // (32,4,256,832)
    const float* trans = (const float*)d_in[2];  // (32,3,3)
    const float* Kmat  = (const float*)d_in[3];  // (32,3,3)
    const float* sz    = (const float*)d_in[4];  // (32,2)
    const float* hcam  = (const float*)d_in[5];  // (32,)
    const float* dimen = (const float*)d_in[6];  // (32,3)
    float* out = (float*)d_out;

    ull* part_keys = (ull*)d_ws;   // 1536*100*8 = 1,228,800 B

    topk_part_kernel<<<B_ * C_ * PARTS, BLK, 0, stream>>>(heat, part_keys);
    merge_geom_kernel<<<B_, BLK, 0, stream>>>(
        part_keys, reg, trans, Kmat, sz, hcam, dimen, out);
}